// Round 1
// baseline (1119.111 us; speedup 1.0000x reference)
//
#include <hip/hip_runtime.h>
#include <math.h>

#define DD 128
#define NEG 0.2f

// ---------------- CSR build ----------------
__global__ void k_hist(const int* __restrict__ dst, int* __restrict__ deg, int E) {
    int i = blockIdx.x * blockDim.x + threadIdx.x;
    if (i < E) atomicAdd(&deg[dst[i]], 1);
}

__global__ void k_scanA(const int* __restrict__ deg, int* __restrict__ tmp,
                        int* __restrict__ blksum, int n) {
    __shared__ int s[256];
    int t = threadIdx.x;
    int base = blockIdx.x * 1024 + t * 4;
    int v0 = 0, v1 = 0, v2 = 0, v3 = 0;
    if (base + 3 < n) {
        int4 q = *(const int4*)(deg + base);
        v0 = q.x; v1 = q.y; v2 = q.z; v3 = q.w;
    } else {
        if (base + 0 < n) v0 = deg[base + 0];
        if (base + 1 < n) v1 = deg[base + 1];
        if (base + 2 < n) v2 = deg[base + 2];
        if (base + 3 < n) v3 = deg[base + 3];
    }
    int p0 = v0, p1 = p0 + v1, p2 = p1 + v2, p3 = p2 + v3;
    s[t] = p3;
    __syncthreads();
    for (int off = 1; off < 256; off <<= 1) {
        int x = (t >= off) ? s[t - off] : 0;
        __syncthreads();
        s[t] += x;
        __syncthreads();
    }
    int excl = s[t] - p3;
    if (base + 0 < n) tmp[base + 0] = excl + p0;
    if (base + 1 < n) tmp[base + 1] = excl + p1;
    if (base + 2 < n) tmp[base + 2] = excl + p2;
    if (base + 3 < n) tmp[base + 3] = excl + p3;
    if (t == 255) blksum[blockIdx.x] = s[255];
}

__global__ void k_scanB(int* blksum, int nb) {
    __shared__ int s[256];
    int t = threadIdx.x;
    int carry = 0;
    for (int base = 0; base < nb; base += 256) {
        int v = (base + t < nb) ? blksum[base + t] : 0;
        s[t] = v;
        __syncthreads();
        for (int off = 1; off < 256; off <<= 1) {
            int x = (t >= off) ? s[t - off] : 0;
            __syncthreads();
            s[t] += x;
            __syncthreads();
        }
        if (base + t < nb) blksum[base + t] = s[t] + carry;
        __syncthreads();
        carry += s[255];
        __syncthreads();
    }
}

// tmp: inclusive-within-chunk from scanA; cursor may alias tmp (read-then-write same idx)
__global__ void k_scanC(const int* tmp, const int* __restrict__ blksum,
                        const int* __restrict__ deg, int* __restrict__ row_ptr,
                        int* cursor, int n) {
    int i = blockIdx.x * blockDim.x + threadIdx.x;
    if (i >= n) return;
    int b = i >> 10;
    int off = b ? blksum[b - 1] : 0;
    int incl = tmp[i] + off;
    row_ptr[i + 1] = incl;
    int dgi = deg[i];
    if (i == 0) row_ptr[0] = 0;
    cursor[i] = incl - dgi;
}

__global__ void k_scatter(const int* __restrict__ src, const int* __restrict__ dst,
                          int* __restrict__ cursor, int* __restrict__ outsrc, int E) {
    int i = blockIdx.x * blockDim.x + threadIdx.x;
    if (i < E) {
        int d = dst[i];
        int p = atomicAdd(&cursor[d], 1);
        outsrc[p] = src[i];
    }
}

// ---------------- fp32 GEMM: C[M,128] = A[M,128] @ W[128,128] ----------------
// block 256 threads, 128 rows per block, 8x8 register tile per thread
__global__ __launch_bounds__(256) void k_gemm(const float* __restrict__ A,
                                              const float* __restrict__ W,
                                              float* __restrict__ C, int M) {
    __shared__ float sA[32][129];   // transposed: sA[k][row]
    __shared__ float sB[32][132];   // sB[k][col]
    int t = threadIdx.x;
    int tx = t & 15;   // col group -> cols tx*8..+8
    int ty = t >> 4;   // row group -> rows ty*8..+8
    int row0 = blockIdx.x * 128;
    float acc[8][8];
#pragma unroll
    for (int i = 0; i < 8; i++)
#pragma unroll
        for (int j = 0; j < 8; j++) acc[i][j] = 0.f;

    for (int k0 = 0; k0 < 128; k0 += 32) {
#pragma unroll
        for (int i = 0; i < 4; i++) {
            int lin = t + i * 256;           // float4 slot
            int r = lin >> 3;                // row in tile (0..127)
            int kq = (lin & 7) << 2;         // k offset (0,4,..,28)
            int gr = row0 + r; gr = gr < M ? gr : M - 1;
            const float4 va = *(const float4*)(A + (size_t)gr * DD + k0 + kq);
            sA[kq + 0][r] = va.x; sA[kq + 1][r] = va.y;
            sA[kq + 2][r] = va.z; sA[kq + 3][r] = va.w;
            int kr = lin >> 5;               // k row (0..31)
            int cq = (lin & 31) << 2;        // col (0,4,..,124)
            const float4 vb = *(const float4*)(W + (size_t)(k0 + kr) * DD + cq);
            *(float4*)&sB[kr][cq] = vb;
        }
        __syncthreads();
#pragma unroll
        for (int k = 0; k < 32; k++) {
            float a[8], b[8];
#pragma unroll
            for (int i = 0; i < 8; i++) a[i] = sA[k][ty * 8 + i];
#pragma unroll
            for (int j = 0; j < 8; j++) b[j] = sB[k][tx * 8 + j];
#pragma unroll
            for (int i = 0; i < 8; i++)
#pragma unroll
                for (int j = 0; j < 8; j++)
                    acc[i][j] = fmaf(a[i], b[j], acc[i][j]);
        }
        __syncthreads();
    }
#pragma unroll
    for (int i = 0; i < 8; i++) {
        int gr = row0 + ty * 8 + i;
        if (gr < M) {
            float4 o0 = {acc[i][0], acc[i][1], acc[i][2], acc[i][3]};
            float4 o1 = {acc[i][4], acc[i][5], acc[i][6], acc[i][7]};
            *(float4*)(C + (size_t)gr * DD + tx * 8) = o0;
            *(float4*)(C + (size_t)gr * DD + tx * 8 + 4) = o1;
        }
    }
}

// ---------------- fused per-dst online-softmax attention + aggregate ----------------
// 16 lanes per dst node, 8 floats per lane. out[d] = (sum_i w_i*xl[src_i]) / sum_i w_i + b
__global__ __launch_bounds__(256) void k_attn(const float* __restrict__ xl,
                                              const float* __restrict__ xr,
                                              const int* __restrict__ row_ptr,
                                              const int* __restrict__ srcs,
                                              const float* __restrict__ att,
                                              const float* __restrict__ bias,
                                              float* __restrict__ out,
                                              int n, int do_relu) {
    int gtid = blockIdx.x * blockDim.x + threadIdx.x;
    int d = gtid >> 4;
    if (d >= n) return;
    int l = threadIdx.x & 15;

    const float4 at0 = *(const float4*)(att + l * 8);
    const float4 at1 = *(const float4*)(att + l * 8 + 4);
    const float* xrp = xr + (size_t)d * DD + l * 8;
    const float4 xr0 = *(const float4*)(xrp);
    const float4 xr1 = *(const float4*)(xrp + 4);

    int beg = row_ptr[d], end = row_ptr[d + 1];
    float m = -INFINITY, lse = 0.f;
    float4 a0 = {0.f, 0.f, 0.f, 0.f}, a1 = {0.f, 0.f, 0.f, 0.f};

    for (int i = beg; i < end; i++) {
        int s = srcs[i];
        const float* xlp = xl + (size_t)s * DD + l * 8;
        float4 x0 = *(const float4*)(xlp);
        float4 x1 = *(const float4*)(xlp + 4);
        float z, p;
        z = x0.x + xr0.x; z = z > 0.f ? z : NEG * z; p  = at0.x * z;
        z = x0.y + xr0.y; z = z > 0.f ? z : NEG * z; p += at0.y * z;
        z = x0.z + xr0.z; z = z > 0.f ? z : NEG * z; p += at0.z * z;
        z = x0.w + xr0.w; z = z > 0.f ? z : NEG * z; p += at0.w * z;
        z = x1.x + xr1.x; z = z > 0.f ? z : NEG * z; p += at1.x * z;
        z = x1.y + xr1.y; z = z > 0.f ? z : NEG * z; p += at1.y * z;
        z = x1.z + xr1.z; z = z > 0.f ? z : NEG * z; p += at1.z * z;
        z = x1.w + xr1.w; z = z > 0.f ? z : NEG * z; p += at1.w * z;
        // reduce across the 16-lane group (xor masks stay within group)
        p += __shfl_xor(p, 1, 64);
        p += __shfl_xor(p, 2, 64);
        p += __shfl_xor(p, 4, 64);
        p += __shfl_xor(p, 8, 64);
        // online softmax update
        float nm = fmaxf(m, p);
        float sc = __expf(m - nm);   // m=-inf first iter -> 0
        float w  = __expf(p - nm);
        a0.x = a0.x * sc + x0.x * w;
        a0.y = a0.y * sc + x0.y * w;
        a0.z = a0.z * sc + x0.z * w;
        a0.w = a0.w * sc + x0.w * w;
        a1.x = a1.x * sc + x1.x * w;
        a1.y = a1.y * sc + x1.y * w;
        a1.z = a1.z * sc + x1.z * w;
        a1.w = a1.w * sc + x1.w * w;
        lse = lse * sc + w;
        m = nm;
    }
    float inv = (end > beg) ? 1.0f / lse : 0.f;
    float4 b0 = *(const float4*)(bias + l * 8);
    float4 b1 = *(const float4*)(bias + l * 8 + 4);
    float4 o0, o1;
    o0.x = a0.x * inv + b0.x; o0.y = a0.y * inv + b0.y;
    o0.z = a0.z * inv + b0.z; o0.w = a0.w * inv + b0.w;
    o1.x = a1.x * inv + b1.x; o1.y = a1.y * inv + b1.y;
    o1.z = a1.z * inv + b1.z; o1.w = a1.w * inv + b1.w;
    if (do_relu) {
        o0.x = fmaxf(o0.x, 0.f); o0.y = fmaxf(o0.y, 0.f);
        o0.z = fmaxf(o0.z, 0.f); o0.w = fmaxf(o0.w, 0.f);
        o1.x = fmaxf(o1.x, 0.f); o1.y = fmaxf(o1.y, 0.f);
        o1.z = fmaxf(o1.z, 0.f); o1.w = fmaxf(o1.w, 0.f);
    }
    float* op = out + (size_t)d * DD + l * 8;
    *(float4*)op = o0;
    *(float4*)(op + 4) = o1;
}

// ---------------- launch ----------------
extern "C" void kernel_launch(void* const* d_in, const int* in_sizes, int n_in,
                              void* d_out, int out_size, void* d_ws, size_t ws_size,
                              hipStream_t stream) {
    const float* x    = (const float*)d_in[0];
    const float* Wl   = (const float*)d_in[1];
    const float* Wr   = (const float*)d_in[2];
    const float* att  = (const float*)d_in[3];
    const float* bias = (const float*)d_in[4];
    const int*   ei   = (const int*)d_in[5];

    int N = in_sizes[0] / DD;
    int E = in_sizes[5] / 2;
    const int* srcI = ei;
    const int* dstI = ei + E;
    float* out = (float*)d_out;

    char* ws = (char*)d_ws;
    size_t off = 0;
    auto alloc = [&](size_t bytes) -> void* {
        void* p = ws + off;
        off += (bytes + 255) & ~(size_t)255;
        return p;
    };
    float* xl      = (float*)alloc((size_t)N * DD * 4);
    float* xr      = (float*)alloc((size_t)N * DD * 4);
    float* hA      = (float*)alloc((size_t)N * DD * 4);
    int*   deg     = (int*)alloc((size_t)N * 4);
    int*   tmp     = (int*)alloc((size_t)N * 4);   // scanA out, then reused as cursor
    int*   row_ptr = (int*)alloc((size_t)(N + 1) * 4);
    int*   blksum  = (int*)alloc(4096);
    int*   srcs    = (int*)alloc((size_t)E * 4);

    const int tb = 256;
    hipMemsetAsync(deg, 0, (size_t)N * 4, stream);
    k_hist<<<(E + tb - 1) / tb, tb, 0, stream>>>(dstI, deg, E);
    int nbA = (N + 1023) / 1024;
    k_scanA<<<nbA, 256, 0, stream>>>(deg, tmp, blksum, N);
    k_scanB<<<1, 256, 0, stream>>>(blksum, nbA);
    k_scanC<<<(N + tb - 1) / tb, tb, 0, stream>>>(tmp, blksum, deg, row_ptr, tmp, N);
    k_scatter<<<(E + tb - 1) / tb, tb, 0, stream>>>(srcI, dstI, tmp, srcs, E);

    const float* hin = x;
    float* houts[3] = {hA, out, out};
    for (int L = 0; L < 3; ++L) {
        k_gemm<<<(N + 127) / 128, 256, 0, stream>>>(hin, Wl + (size_t)L * DD * DD, xl, N);
        k_gemm<<<(N + 127) / 128, 256, 0, stream>>>(hin, Wr + (size_t)L * DD * DD, xr, N);
        k_attn<<<((size_t)N * 16 + tb - 1) / tb, tb, 0, stream>>>(
            xl, xr, row_ptr, srcs, att + (size_t)L * DD, bias + (size_t)L * DD,
            houts[L], N, (L < 2) ? 1 : 0);
        hin = houts[L];
    }
}

// Round 2
// 791.469 us; speedup vs baseline: 1.4140x; 1.4140x over previous
//
#include <hip/hip_runtime.h>
#include <math.h>

#define DD 128
#define NEG 0.2f

typedef short short8 __attribute__((ext_vector_type(8)));
typedef float f32x4 __attribute__((ext_vector_type(4)));

__device__ __forceinline__ unsigned short f2bf(float f) {
    unsigned u = __float_as_uint(f);
    return (unsigned short)((u + 0x7fffu + ((u >> 16) & 1u)) >> 16);
}
__device__ __forceinline__ float bf2f(unsigned short h) {
    return __uint_as_float(((unsigned)h) << 16);
}

// ---------------- CSR build ----------------
__global__ void k_hist(const int* __restrict__ dst, int* __restrict__ deg, int E) {
    int i = blockIdx.x * blockDim.x + threadIdx.x;
    if (i < E) atomicAdd(&deg[dst[i]], 1);
}

__global__ void k_scanA(const int* __restrict__ deg, int* __restrict__ tmp,
                        int* __restrict__ blksum, int n) {
    __shared__ int s[256];
    int t = threadIdx.x;
    int base = blockIdx.x * 1024 + t * 4;
    int v0 = 0, v1 = 0, v2 = 0, v3 = 0;
    if (base + 3 < n) {
        int4 q = *(const int4*)(deg + base);
        v0 = q.x; v1 = q.y; v2 = q.z; v3 = q.w;
    } else {
        if (base + 0 < n) v0 = deg[base + 0];
        if (base + 1 < n) v1 = deg[base + 1];
        if (base + 2 < n) v2 = deg[base + 2];
        if (base + 3 < n) v3 = deg[base + 3];
    }
    int p0 = v0, p1 = p0 + v1, p2 = p1 + v2, p3 = p2 + v3;
    s[t] = p3;
    __syncthreads();
    for (int off = 1; off < 256; off <<= 1) {
        int x = (t >= off) ? s[t - off] : 0;
        __syncthreads();
        s[t] += x;
        __syncthreads();
    }
    int excl = s[t] - p3;
    if (base + 0 < n) tmp[base + 0] = excl + p0;
    if (base + 1 < n) tmp[base + 1] = excl + p1;
    if (base + 2 < n) tmp[base + 2] = excl + p2;
    if (base + 3 < n) tmp[base + 3] = excl + p3;
    if (t == 255) blksum[blockIdx.x] = s[255];
}

__global__ void k_scanB(int* blksum, int nb) {
    __shared__ int s[256];
    int t = threadIdx.x;
    int carry = 0;
    for (int base = 0; base < nb; base += 256) {
        int v = (base + t < nb) ? blksum[base + t] : 0;
        s[t] = v;
        __syncthreads();
        for (int off = 1; off < 256; off <<= 1) {
            int x = (t >= off) ? s[t - off] : 0;
            __syncthreads();
            s[t] += x;
            __syncthreads();
        }
        if (base + t < nb) blksum[base + t] = s[t] + carry;
        __syncthreads();
        carry += s[255];
        __syncthreads();
    }
}

__global__ void k_scanC(const int* tmp, const int* __restrict__ blksum,
                        const int* __restrict__ deg, int* __restrict__ row_ptr,
                        int* cursor, int n) {
    int i = blockIdx.x * blockDim.x + threadIdx.x;
    if (i >= n) return;
    int b = i >> 10;
    int off = b ? blksum[b - 1] : 0;
    int incl = tmp[i] + off;
    row_ptr[i + 1] = incl;
    int dgi = deg[i];
    if (i == 0) row_ptr[0] = 0;
    cursor[i] = incl - dgi;
}

__global__ void k_scatter(const int* __restrict__ src, const int* __restrict__ dst,
                          int* __restrict__ cursor, int* __restrict__ outsrc, int E) {
    int i = blockIdx.x * blockDim.x + threadIdx.x;
    if (i < E) {
        int d = dst[i];
        int p = atomicAdd(&cursor[d], 1);
        outsrc[p] = src[i];
    }
}

// ---------------- split-float cast kernels ----------------
// x fp32 [n] -> hi,lo bf16 (x ~= hi + lo, error ~2^-17 rel)
__global__ void k_castx(const float* __restrict__ x, unsigned short* __restrict__ hi,
                        unsigned short* __restrict__ lo, int n) {
    int i = (blockIdx.x * blockDim.x + threadIdx.x) * 4;
    if (i >= n) return;
    float4 v = *(const float4*)(x + i);
    unsigned short h[4], l[4];
    float f[4] = {v.x, v.y, v.z, v.w};
#pragma unroll
    for (int j = 0; j < 4; j++) {
        h[j] = f2bf(f[j]);
        l[j] = f2bf(f[j] - bf2f(h[j]));
    }
    *(uint2*)(hi + i) = *(uint2*)h;
    *(uint2*)(lo + i) = *(uint2*)l;
}

// Build transposed fused weight Wt[L][n][k], n in [0,256): n<128 -> Wl, else Wr.
// Wl/Wr are [L][k][n'] row-major.
__global__ void k_castw(const float* __restrict__ Wl, const float* __restrict__ Wr,
                        unsigned short* __restrict__ Wth, unsigned short* __restrict__ Wtl) {
    int idx = blockIdx.x * blockDim.x + threadIdx.x;
    if (idx >= 3 * 256 * 128) return;
    int L = idx >> 15;
    int rem = idx & 32767;
    int nn = rem >> 7;
    int k = rem & 127;
    float v = (nn < 128) ? Wl[L * 16384 + k * 128 + nn]
                         : Wr[L * 16384 + k * 128 + (nn - 128)];
    unsigned short h = f2bf(v);
    Wth[idx] = h;
    Wtl[idx] = f2bf(v - bf2f(h));
}

// ---------------- MFMA GEMM: [xl|xr][M,128each] = A[M,128] @ W[128,256] ----------------
// A given as hi/lo bf16 pair; W as transposed hi/lo Wt[n][k]. 3-product split-float.
// block 256 thr (4 waves), tile 128(M) x 128(N), gridDim.y picks xl (0) or xr (1).
__global__ __launch_bounds__(256) void k_gemm(const unsigned short* __restrict__ Ahi,
                                              const unsigned short* __restrict__ Alo,
                                              const unsigned short* __restrict__ Wth,
                                              const unsigned short* __restrict__ Wtl,
                                              float* __restrict__ xl, float* __restrict__ xr,
                                              int M, int L) {
    __shared__ unsigned short sA[2][128][40];  // [term][row][k] pad->free 2-way
    __shared__ unsigned short sB[2][128][40];  // [term][n][k]
    int t = threadIdx.x;
    int lane = t & 63;
    int l15 = lane & 15;
    int quad = lane >> 4;
    int wave = t >> 6;
    int wm = wave & 1;    // m-offset 0/64
    int wn = wave >> 1;   // n-offset 0/64
    int r0 = blockIdx.x * 128;
    const unsigned short* WthL = Wth + ((size_t)L * 256 + blockIdx.y * 128) * 128;
    const unsigned short* WtlL = Wtl + ((size_t)L * 256 + blockIdx.y * 128) * 128;

    f32x4 acc[4][4] = {};

    for (int kc = 0; kc < 4; kc++) {
        int k0 = kc * 32;
        if (kc) __syncthreads();
        // stage A (128 rows x 32 k) hi+lo and B (128 n x 32 k) hi+lo
#pragma unroll
        for (int i = 0; i < 2; i++) {
            int s = t + i * 256;          // 512 slots of 8 bf16
            int row = s >> 2;
            int kq = (s & 3) * 8;
            int gr = r0 + row; gr = gr < M ? gr : M - 1;
            uint2 va0 = *(const uint2*)(Ahi + (size_t)gr * DD + k0 + kq);
            uint2 va1 = *(const uint2*)(Ahi + (size_t)gr * DD + k0 + kq + 4);
            *(uint2*)&sA[0][row][kq] = va0;
            *(uint2*)&sA[0][row][kq + 4] = va1;
            uint2 vb0 = *(const uint2*)(Alo + (size_t)gr * DD + k0 + kq);
            uint2 vb1 = *(const uint2*)(Alo + (size_t)gr * DD + k0 + kq + 4);
            *(uint2*)&sA[1][row][kq] = vb0;
            *(uint2*)&sA[1][row][kq + 4] = vb1;
            uint2 wa0 = *(const uint2*)(WthL + (size_t)row * DD + k0 + kq);
            uint2 wa1 = *(const uint2*)(WthL + (size_t)row * DD + k0 + kq + 4);
            *(uint2*)&sB[0][row][kq] = wa0;
            *(uint2*)&sB[0][row][kq + 4] = wa1;
            uint2 wb0 = *(const uint2*)(WtlL + (size_t)row * DD + k0 + kq);
            uint2 wb1 = *(const uint2*)(WtlL + (size_t)row * DD + k0 + kq + 4);
            *(uint2*)&sB[1][row][kq] = wb0;
            *(uint2*)&sB[1][row][kq + 4] = wb1;
        }
        __syncthreads();

        union F8 { short8 v; uint2 u[2]; };
        F8 ah[4], al[4], bh[4], bl[4];
#pragma unroll
        for (int mt = 0; mt < 4; mt++) {
            const unsigned short* p = &sA[0][wm * 64 + mt * 16 + l15][quad * 8];
            ah[mt].u[0] = *(const uint2*)p; ah[mt].u[1] = *(const uint2*)(p + 4);
            const unsigned short* q = &sA[1][wm * 64 + mt * 16 + l15][quad * 8];
            al[mt].u[0] = *(const uint2*)q; al[mt].u[1] = *(const uint2*)(q + 4);
        }
#pragma unroll
        for (int nt = 0; nt < 4; nt++) {
            const unsigned short* p = &sB[0][wn * 64 + nt * 16 + l15][quad * 8];
            bh[nt].u[0] = *(const uint2*)p; bh[nt].u[1] = *(const uint2*)(p + 4);
            const unsigned short* q = &sB[1][wn * 64 + nt * 16 + l15][quad * 8];
            bl[nt].u[0] = *(const uint2*)q; bl[nt].u[1] = *(const uint2*)(q + 4);
        }
#pragma unroll
        for (int mt = 0; mt < 4; mt++)
#pragma unroll
            for (int nt = 0; nt < 4; nt++) {
                acc[mt][nt] = __builtin_amdgcn_mfma_f32_16x16x32_bf16(ah[mt].v, bh[nt].v, acc[mt][nt], 0, 0, 0);
                acc[mt][nt] = __builtin_amdgcn_mfma_f32_16x16x32_bf16(al[mt].v, bh[nt].v, acc[mt][nt], 0, 0, 0);
                acc[mt][nt] = __builtin_amdgcn_mfma_f32_16x16x32_bf16(ah[mt].v, bl[nt].v, acc[mt][nt], 0, 0, 0);
            }
    }

    float* C = blockIdx.y ? xr : xl;
#pragma unroll
    for (int mt = 0; mt < 4; mt++)
#pragma unroll
        for (int r = 0; r < 4; r++) {
            int row = r0 + wm * 64 + mt * 16 + quad * 4 + r;
            if (row < M) {
#pragma unroll
                for (int nt = 0; nt < 4; nt++)
                    C[(size_t)row * DD + wn * 64 + nt * 16 + l15] = acc[mt][nt][r];
            }
        }
}

// ---------------- fused per-dst online-softmax attention + aggregate ----------------
// 16 lanes per dst, 8 floats/lane. mode 1: relu + write bf16 hi/lo (next layer input);
// mode 0: write fp32 (final output), no relu.
__global__ __launch_bounds__(256) void k_attn(const float* __restrict__ xl,
                                              const float* __restrict__ xr,
                                              const int* __restrict__ row_ptr,
                                              const int* __restrict__ srcs,
                                              const float* __restrict__ att,
                                              const float* __restrict__ bias,
                                              float* __restrict__ outF,
                                              unsigned short* __restrict__ outHi,
                                              unsigned short* __restrict__ outLo,
                                              int n, int mode) {
    int gtid = blockIdx.x * blockDim.x + threadIdx.x;
    int d = gtid >> 4;
    if (d >= n) return;
    int l = threadIdx.x & 15;

    const float4 at0 = *(const float4*)(att + l * 8);
    const float4 at1 = *(const float4*)(att + l * 8 + 4);
    const float* xrp = xr + (size_t)d * DD + l * 8;
    const float4 xr0 = *(const float4*)(xrp);
    const float4 xr1 = *(const float4*)(xrp + 4);

    int beg = row_ptr[d], end = row_ptr[d + 1];
    float m = -INFINITY, lse = 0.f;
    float4 a0 = {0.f, 0.f, 0.f, 0.f}, a1 = {0.f, 0.f, 0.f, 0.f};

    for (int i = beg; i < end; i++) {
        int s = srcs[i];
        const float* xlp = xl + (size_t)s * DD + l * 8;
        float4 x0 = *(const float4*)(xlp);
        float4 x1 = *(const float4*)(xlp + 4);
        float z, p;
        z = x0.x + xr0.x; z = z > 0.f ? z : NEG * z; p  = at0.x * z;
        z = x0.y + xr0.y; z = z > 0.f ? z : NEG * z; p += at0.y * z;
        z = x0.z + xr0.z; z = z > 0.f ? z : NEG * z; p += at0.z * z;
        z = x0.w + xr0.w; z = z > 0.f ? z : NEG * z; p += at0.w * z;
        z = x1.x + xr1.x; z = z > 0.f ? z : NEG * z; p += at1.x * z;
        z = x1.y + xr1.y; z = z > 0.f ? z : NEG * z; p += at1.y * z;
        z = x1.z + xr1.z; z = z > 0.f ? z : NEG * z; p += at1.z * z;
        z = x1.w + xr1.w; z = z > 0.f ? z : NEG * z; p += at1.w * z;
        p += __shfl_xor(p, 1, 64);
        p += __shfl_xor(p, 2, 64);
        p += __shfl_xor(p, 4, 64);
        p += __shfl_xor(p, 8, 64);
        float nm = fmaxf(m, p);
        float sc = __expf(m - nm);
        float w  = __expf(p - nm);
        a0.x = a0.x * sc + x0.x * w;
        a0.y = a0.y * sc + x0.y * w;
        a0.z = a0.z * sc + x0.z * w;
        a0.w = a0.w * sc + x0.w * w;
        a1.x = a1.x * sc + x1.x * w;
        a1.y = a1.y * sc + x1.y * w;
        a1.z = a1.z * sc + x1.z * w;
        a1.w = a1.w * sc + x1.w * w;
        lse = lse * sc + w;
        m = nm;
    }
    float inv = (end > beg) ? 1.0f / lse : 0.f;
    float4 b0 = *(const float4*)(bias + l * 8);
    float4 b1 = *(const float4*)(bias + l * 8 + 4);
    float o[8];
    o[0] = a0.x * inv + b0.x; o[1] = a0.y * inv + b0.y;
    o[2] = a0.z * inv + b0.z; o[3] = a0.w * inv + b0.w;
    o[4] = a1.x * inv + b1.x; o[5] = a1.y * inv + b1.y;
    o[6] = a1.z * inv + b1.z; o[7] = a1.w * inv + b1.w;
    if (mode) {
        union U8 { unsigned short s[8]; uint4 q; };
        U8 hh, ll;
#pragma unroll
        for (int j = 0; j < 8; j++) {
            float v = fmaxf(o[j], 0.f);
            hh.s[j] = f2bf(v);
            ll.s[j] = f2bf(v - bf2f(hh.s[j]));
        }
        *(uint4*)(outHi + (size_t)d * DD + l * 8) = hh.q;
        *(uint4*)(outLo + (size_t)d * DD + l * 8) = ll.q;
    } else {
        float* op = outF + (size_t)d * DD + l * 8;
        float4 o0 = {o[0], o[1], o[2], o[3]};
        float4 o1 = {o[4], o[5], o[6], o[7]};
        *(float4*)op = o0;
        *(float4*)(op + 4) = o1;
    }
}

// ---------------- launch ----------------
extern "C" void kernel_launch(void* const* d_in, const int* in_sizes, int n_in,
                              void* d_out, int out_size, void* d_ws, size_t ws_size,
                              hipStream_t stream) {
    const float* x    = (const float*)d_in[0];
    const float* Wl   = (const float*)d_in[1];
    const float* Wr   = (const float*)d_in[2];
    const float* att  = (const float*)d_in[3];
    const float* bias = (const float*)d_in[4];
    const int*   ei   = (const int*)d_in[5];

    int N = in_sizes[0] / DD;
    int E = in_sizes[5] / 2;
    const int* srcI = ei;
    const int* dstI = ei + E;
    float* out = (float*)d_out;

    char* ws = (char*)d_ws;
    size_t off = 0;
    auto alloc = [&](size_t bytes) -> void* {
        void* p = ws + off;
        off += (bytes + 255) & ~(size_t)255;
        return p;
    };
    float*          xl   = (float*)alloc((size_t)N * DD * 4);
    float*          xr   = (float*)alloc((size_t)N * DD * 4);
    unsigned short* Ahi  = (unsigned short*)alloc((size_t)N * DD * 2);
    unsigned short* Alo  = (unsigned short*)alloc((size_t)N * DD * 2);
    unsigned short* Wth  = (unsigned short*)alloc((size_t)3 * 256 * 128 * 2);
    unsigned short* Wtl  = (unsigned short*)alloc((size_t)3 * 256 * 128 * 2);
    int*   deg     = (int*)alloc((size_t)N * 4);
    int*   tmp     = (int*)alloc((size_t)N * 4);
    int*   row_ptr = (int*)alloc((size_t)(N + 1) * 4);
    int*   blksum  = (int*)alloc(4096);
    int*   srcs    = (int*)alloc((size_t)E * 4);

    const int tb = 256;
    // CSR build
    hipMemsetAsync(deg, 0, (size_t)N * 4, stream);
    k_hist<<<(E + tb - 1) / tb, tb, 0, stream>>>(dstI, deg, E);
    int nbA = (N + 1023) / 1024;
    k_scanA<<<nbA, 256, 0, stream>>>(deg, tmp, blksum, N);
    k_scanB<<<1, 256, 0, stream>>>(blksum, nbA);
    k_scanC<<<(N + tb - 1) / tb, tb, 0, stream>>>(tmp, blksum, deg, row_ptr, tmp, N);
    k_scatter<<<(E + tb - 1) / tb, tb, 0, stream>>>(srcI, dstI, tmp, srcs, E);

    // weight + input casts
    k_castw<<<(3 * 256 * 128 + tb - 1) / tb, tb, 0, stream>>>(Wl, Wr, Wth, Wtl);
    k_castx<<<((size_t)N * DD / 4 + tb - 1) / tb, tb, 0, stream>>>(x, Ahi, Alo, N * DD);

    int gX = (N + 127) / 128;
    for (int L = 0; L < 3; ++L) {
        k_gemm<<<dim3(gX, 2), 256, 0, stream>>>(Ahi, Alo, Wth, Wtl, xl, xr, N, L);
        k_attn<<<((size_t)N * 16 + tb - 1) / tb, tb, 0, stream>>>(
            xl, xr, row_ptr, srcs, att + (size_t)L * DD, bias + (size_t)L * DD,
            out, Ahi, Alo, N, (L < 2) ? 1 : 0);
    }
}

// Round 3
// 675.606 us; speedup vs baseline: 1.6565x; 1.1715x over previous
//
#include <hip/hip_runtime.h>
#include <math.h>

#define DD 128
#define NEG 0.2f

typedef short short8 __attribute__((ext_vector_type(8)));
typedef float f32x4 __attribute__((ext_vector_type(4)));

__device__ __forceinline__ unsigned short f2bf(float f) {
    unsigned u = __float_as_uint(f);
    return (unsigned short)((u + 0x7fffu + ((u >> 16) & 1u)) >> 16);
}
__device__ __forceinline__ float bf2f(unsigned short h) {
    return __uint_as_float(((unsigned)h) << 16);
}

// ---------------- CSR build ----------------
__global__ void k_hist(const int* __restrict__ dst, int* __restrict__ deg, int E) {
    int i = blockIdx.x * blockDim.x + threadIdx.x;
    if (i < E) atomicAdd(&deg[dst[i]], 1);
}

__global__ void k_scanA(const int* __restrict__ deg, int* __restrict__ tmp,
                        int* __restrict__ blksum, int n) {
    __shared__ int s[256];
    int t = threadIdx.x;
    int base = blockIdx.x * 1024 + t * 4;
    int v0 = 0, v1 = 0, v2 = 0, v3 = 0;
    if (base + 3 < n) {
        int4 q = *(const int4*)(deg + base);
        v0 = q.x; v1 = q.y; v2 = q.z; v3 = q.w;
    } else {
        if (base + 0 < n) v0 = deg[base + 0];
        if (base + 1 < n) v1 = deg[base + 1];
        if (base + 2 < n) v2 = deg[base + 2];
        if (base + 3 < n) v3 = deg[base + 3];
    }
    int p0 = v0, p1 = p0 + v1, p2 = p1 + v2, p3 = p2 + v3;
    s[t] = p3;
    __syncthreads();
    for (int off = 1; off < 256; off <<= 1) {
        int x = (t >= off) ? s[t - off] : 0;
        __syncthreads();
        s[t] += x;
        __syncthreads();
    }
    int excl = s[t] - p3;
    if (base + 0 < n) tmp[base + 0] = excl + p0;
    if (base + 1 < n) tmp[base + 1] = excl + p1;
    if (base + 2 < n) tmp[base + 2] = excl + p2;
    if (base + 3 < n) tmp[base + 3] = excl + p3;
    if (t == 255) blksum[blockIdx.x] = s[255];
}

__global__ void k_scanB(int* blksum, int nb) {
    __shared__ int s[256];
    int t = threadIdx.x;
    int carry = 0;
    for (int base = 0; base < nb; base += 256) {
        int v = (base + t < nb) ? blksum[base + t] : 0;
        s[t] = v;
        __syncthreads();
        for (int off = 1; off < 256; off <<= 1) {
            int x = (t >= off) ? s[t - off] : 0;
            __syncthreads();
            s[t] += x;
            __syncthreads();
        }
        if (base + t < nb) blksum[base + t] = s[t] + carry;
        __syncthreads();
        carry += s[255];
        __syncthreads();
    }
}

__global__ void k_scanC(const int* tmp, const int* __restrict__ blksum,
                        const int* __restrict__ deg, int* __restrict__ row_ptr,
                        int* cursor, int n) {
    int i = blockIdx.x * blockDim.x + threadIdx.x;
    if (i >= n) return;
    int b = i >> 10;
    int off = b ? blksum[b - 1] : 0;
    int incl = tmp[i] + off;
    row_ptr[i + 1] = incl;
    int dgi = deg[i];
    if (i == 0) row_ptr[0] = 0;
    cursor[i] = incl - dgi;
}

__global__ void k_scatter(const int* __restrict__ src, const int* __restrict__ dst,
                          int* __restrict__ cursor, int* __restrict__ outsrc, int E) {
    int i = blockIdx.x * blockDim.x + threadIdx.x;
    if (i < E) {
        int d = dst[i];
        int p = atomicAdd(&cursor[d], 1);
        outsrc[p] = src[i];
    }
}

// ---------------- split-float cast kernels ----------------
__global__ void k_castx(const float* __restrict__ x, unsigned short* __restrict__ hi,
                        unsigned short* __restrict__ lo, int n) {
    int i = (blockIdx.x * blockDim.x + threadIdx.x) * 4;
    if (i >= n) return;
    float4 v = *(const float4*)(x + i);
    unsigned short h[4], l[4];
    float f[4] = {v.x, v.y, v.z, v.w};
#pragma unroll
    for (int j = 0; j < 4; j++) {
        h[j] = f2bf(f[j]);
        l[j] = f2bf(f[j] - bf2f(h[j]));
    }
    *(uint2*)(hi + i) = *(uint2*)h;
    *(uint2*)(lo + i) = *(uint2*)l;
}

// Build transposed fused weight Wt[L][n][k], n in [0,256): n<128 -> Wl, else Wr.
__global__ void k_castw(const float* __restrict__ Wl, const float* __restrict__ Wr,
                        unsigned short* __restrict__ Wth, unsigned short* __restrict__ Wtl) {
    int idx = blockIdx.x * blockDim.x + threadIdx.x;
    if (idx >= 3 * 256 * 128) return;
    int L = idx >> 15;
    int rem = idx & 32767;
    int nn = rem >> 7;
    int k = rem & 127;
    float v = (nn < 128) ? Wl[L * 16384 + k * 128 + nn]
                         : Wr[L * 16384 + k * 128 + (nn - 128)];
    unsigned short h = f2bf(v);
    Wth[idx] = h;
    Wtl[idx] = f2bf(v - bf2f(h));
}

// ---------------- MFMA GEMM: [xl|xr][M,128each] = A[M,128] @ W[128,256] ----------------
// A as hi/lo bf16; W transposed hi/lo. 3-product split-float. Output fp16.
__global__ __launch_bounds__(256) void k_gemm(const unsigned short* __restrict__ Ahi,
                                              const unsigned short* __restrict__ Alo,
                                              const unsigned short* __restrict__ Wth,
                                              const unsigned short* __restrict__ Wtl,
                                              _Float16* __restrict__ xl, _Float16* __restrict__ xr,
                                              int M, int L) {
    __shared__ unsigned short sA[2][128][40];
    __shared__ unsigned short sB[2][128][40];
    int t = threadIdx.x;
    int lane = t & 63;
    int l15 = lane & 15;
    int quad = lane >> 4;
    int wave = t >> 6;
    int wm = wave & 1;
    int wn = wave >> 1;
    int r0 = blockIdx.x * 128;
    const unsigned short* WthL = Wth + ((size_t)L * 256 + blockIdx.y * 128) * 128;
    const unsigned short* WtlL = Wtl + ((size_t)L * 256 + blockIdx.y * 128) * 128;

    f32x4 acc[4][4] = {};

    for (int kc = 0; kc < 4; kc++) {
        int k0 = kc * 32;
        if (kc) __syncthreads();
#pragma unroll
        for (int i = 0; i < 2; i++) {
            int s = t + i * 256;
            int row = s >> 2;
            int kq = (s & 3) * 8;
            int gr = r0 + row; gr = gr < M ? gr : M - 1;
            uint2 va0 = *(const uint2*)(Ahi + (size_t)gr * DD + k0 + kq);
            uint2 va1 = *(const uint2*)(Ahi + (size_t)gr * DD + k0 + kq + 4);
            *(uint2*)&sA[0][row][kq] = va0;
            *(uint2*)&sA[0][row][kq + 4] = va1;
            uint2 vb0 = *(const uint2*)(Alo + (size_t)gr * DD + k0 + kq);
            uint2 vb1 = *(const uint2*)(Alo + (size_t)gr * DD + k0 + kq + 4);
            *(uint2*)&sA[1][row][kq] = vb0;
            *(uint2*)&sA[1][row][kq + 4] = vb1;
            uint2 wa0 = *(const uint2*)(WthL + (size_t)row * DD + k0 + kq);
            uint2 wa1 = *(const uint2*)(WthL + (size_t)row * DD + k0 + kq + 4);
            *(uint2*)&sB[0][row][kq] = wa0;
            *(uint2*)&sB[0][row][kq + 4] = wa1;
            uint2 wb0 = *(const uint2*)(WtlL + (size_t)row * DD + k0 + kq);
            uint2 wb1 = *(const uint2*)(WtlL + (size_t)row * DD + k0 + kq + 4);
            *(uint2*)&sB[1][row][kq] = wb0;
            *(uint2*)&sB[1][row][kq + 4] = wb1;
        }
        __syncthreads();

        union F8 { short8 v; uint2 u[2]; };
        F8 ah[4], al[4], bh[4], bl[4];
#pragma unroll
        for (int mt = 0; mt < 4; mt++) {
            const unsigned short* p = &sA[0][wm * 64 + mt * 16 + l15][quad * 8];
            ah[mt].u[0] = *(const uint2*)p; ah[mt].u[1] = *(const uint2*)(p + 4);
            const unsigned short* q = &sA[1][wm * 64 + mt * 16 + l15][quad * 8];
            al[mt].u[0] = *(const uint2*)q; al[mt].u[1] = *(const uint2*)(q + 4);
        }
#pragma unroll
        for (int nt = 0; nt < 4; nt++) {
            const unsigned short* p = &sB[0][wn * 64 + nt * 16 + l15][quad * 8];
            bh[nt].u[0] = *(const uint2*)p; bh[nt].u[1] = *(const uint2*)(p + 4);
            const unsigned short* q = &sB[1][wn * 64 + nt * 16 + l15][quad * 8];
            bl[nt].u[0] = *(const uint2*)q; bl[nt].u[1] = *(const uint2*)(q + 4);
        }
#pragma unroll
        for (int mt = 0; mt < 4; mt++)
#pragma unroll
            for (int nt = 0; nt < 4; nt++) {
                acc[mt][nt] = __builtin_amdgcn_mfma_f32_16x16x32_bf16(ah[mt].v, bh[nt].v, acc[mt][nt], 0, 0, 0);
                acc[mt][nt] = __builtin_amdgcn_mfma_f32_16x16x32_bf16(al[mt].v, bh[nt].v, acc[mt][nt], 0, 0, 0);
                acc[mt][nt] = __builtin_amdgcn_mfma_f32_16x16x32_bf16(ah[mt].v, bl[nt].v, acc[mt][nt], 0, 0, 0);
            }
    }

    _Float16* C = blockIdx.y ? xr : xl;
#pragma unroll
    for (int mt = 0; mt < 4; mt++)
#pragma unroll
        for (int r = 0; r < 4; r++) {
            int row = r0 + wm * 64 + mt * 16 + quad * 4 + r;
            if (row < M) {
#pragma unroll
                for (int nt = 0; nt < 4; nt++)
                    C[(size_t)row * DD + wn * 64 + nt * 16 + l15] = (_Float16)acc[mt][nt][r];
            }
        }
}

// ---------------- fused per-dst online-softmax attention + aggregate ----------------
// 16 lanes per dst, 8 elems/lane. xl/xr are fp16. mode 1: relu + write bf16 hi/lo;
// mode 0: write fp32 final output.
__global__ __launch_bounds__(256) void k_attn(const _Float16* __restrict__ xl,
                                              const _Float16* __restrict__ xr,
                                              const int* __restrict__ row_ptr,
                                              const int* __restrict__ srcs,
                                              const float* __restrict__ att,
                                              const float* __restrict__ bias,
                                              float* __restrict__ outF,
                                              unsigned short* __restrict__ outHi,
                                              unsigned short* __restrict__ outLo,
                                              int n, int mode) {
    int gtid = blockIdx.x * blockDim.x + threadIdx.x;
    int d = gtid >> 4;
    if (d >= n) return;
    int l = threadIdx.x & 15;

    union H8 { uint4 q; _Float16 h[8]; };

    float atv[8], xrv[8];
    {
        float4 a0 = *(const float4*)(att + l * 8);
        float4 a1 = *(const float4*)(att + l * 8 + 4);
        atv[0] = a0.x; atv[1] = a0.y; atv[2] = a0.z; atv[3] = a0.w;
        atv[4] = a1.x; atv[5] = a1.y; atv[6] = a1.z; atv[7] = a1.w;
        H8 hr; hr.q = *(const uint4*)(xr + (size_t)d * DD + l * 8);
#pragma unroll
        for (int j = 0; j < 8; j++) xrv[j] = (float)hr.h[j];
    }

    int beg = row_ptr[d], end = row_ptr[d + 1];
    float m = -INFINITY, lse = 0.f;
    float av[8] = {0.f, 0.f, 0.f, 0.f, 0.f, 0.f, 0.f, 0.f};

    for (int i = beg; i < end; i++) {
        int s = srcs[i];
        H8 hx; hx.q = *(const uint4*)(xl + (size_t)s * DD + l * 8);
        float xv[8];
#pragma unroll
        for (int j = 0; j < 8; j++) xv[j] = (float)hx.h[j];
        float p = 0.f;
#pragma unroll
        for (int j = 0; j < 8; j++) {
            float z = xv[j] + xrv[j];
            z = z > 0.f ? z : NEG * z;
            p = fmaf(atv[j], z, p);
        }
        p += __shfl_xor(p, 1, 64);
        p += __shfl_xor(p, 2, 64);
        p += __shfl_xor(p, 4, 64);
        p += __shfl_xor(p, 8, 64);
        float nm = fmaxf(m, p);
        float sc = __expf(m - nm);
        float w  = __expf(p - nm);
#pragma unroll
        for (int j = 0; j < 8; j++) av[j] = av[j] * sc + xv[j] * w;
        lse = lse * sc + w;
        m = nm;
    }
    float inv = (end > beg) ? 1.0f / lse : 0.f;
    float o[8];
    {
        float4 b0 = *(const float4*)(bias + l * 8);
        float4 b1 = *(const float4*)(bias + l * 8 + 4);
        float bv[8] = {b0.x, b0.y, b0.z, b0.w, b1.x, b1.y, b1.z, b1.w};
#pragma unroll
        for (int j = 0; j < 8; j++) o[j] = av[j] * inv + bv[j];
    }
    if (mode) {
        union U8 { unsigned short s[8]; uint4 q; };
        U8 hh, ll;
#pragma unroll
        for (int j = 0; j < 8; j++) {
            float v = fmaxf(o[j], 0.f);
            hh.s[j] = f2bf(v);
            ll.s[j] = f2bf(v - bf2f(hh.s[j]));
        }
        *(uint4*)(outHi + (size_t)d * DD + l * 8) = hh.q;
        *(uint4*)(outLo + (size_t)d * DD + l * 8) = ll.q;
    } else {
        float4 o0 = {o[0], o[1], o[2], o[3]};
        float4 o1 = {o[4], o[5], o[6], o[7]};
        float* op = outF + (size_t)d * DD + l * 8;
        *(float4*)op = o0;
        *(float4*)(op + 4) = o1;
    }
}

// ---------------- launch ----------------
extern "C" void kernel_launch(void* const* d_in, const int* in_sizes, int n_in,
                              void* d_out, int out_size, void* d_ws, size_t ws_size,
                              hipStream_t stream) {
    const float* x    = (const float*)d_in[0];
    const float* Wl   = (const float*)d_in[1];
    const float* Wr   = (const float*)d_in[2];
    const float* att  = (const float*)d_in[3];
    const float* bias = (const float*)d_in[4];
    const int*   ei   = (const int*)d_in[5];

    int N = in_sizes[0] / DD;
    int E = in_sizes[5] / 2;
    const int* srcI = ei;
    const int* dstI = ei + E;
    float* out = (float*)d_out;

    char* ws = (char*)d_ws;
    size_t off = 0;
    auto alloc = [&](size_t bytes) -> void* {
        void* p = ws + off;
        off += (bytes + 255) & ~(size_t)255;
        return p;
    };
    _Float16*       xl   = (_Float16*)alloc((size_t)N * DD * 2);
    _Float16*       xr   = (_Float16*)alloc((size_t)N * DD * 2);
    unsigned short* Ahi  = (unsigned short*)alloc((size_t)N * DD * 2);
    unsigned short* Alo  = (unsigned short*)alloc((size_t)N * DD * 2);
    unsigned short* Wth  = (unsigned short*)alloc((size_t)3 * 256 * 128 * 2);
    unsigned short* Wtl  = (unsigned short*)alloc((size_t)3 * 256 * 128 * 2);
    int*   deg     = (int*)alloc((size_t)N * 4);
    int*   tmp     = (int*)alloc((size_t)N * 4);
    int*   row_ptr = (int*)alloc((size_t)(N + 1) * 4);
    int*   blksum  = (int*)alloc(4096);
    int*   srcs    = (int*)alloc((size_t)E * 4);

    const int tb = 256;
    hipMemsetAsync(deg, 0, (size_t)N * 4, stream);
    k_hist<<<(E + tb - 1) / tb, tb, 0, stream>>>(dstI, deg, E);
    int nbA = (N + 1023) / 1024;
    k_scanA<<<nbA, 256, 0, stream>>>(deg, tmp, blksum, N);
    k_scanB<<<1, 256, 0, stream>>>(blksum, nbA);
    k_scanC<<<(N + tb - 1) / tb, tb, 0, stream>>>(tmp, blksum, deg, row_ptr, tmp, N);
    k_scatter<<<(E + tb - 1) / tb, tb, 0, stream>>>(srcI, dstI, tmp, srcs, E);

    k_castw<<<(3 * 256 * 128 + tb - 1) / tb, tb, 0, stream>>>(Wl, Wr, Wth, Wtl);
    k_castx<<<((size_t)N * DD / 4 + tb - 1) / tb, tb, 0, stream>>>(x, Ahi, Alo, N * DD);

    int gX = (N + 127) / 128;
    for (int L = 0; L < 3; ++L) {
        k_gemm<<<dim3(gX, 2), 256, 0, stream>>>(Ahi, Alo, Wth, Wtl, xl, xr, N, L);
        k_attn<<<((size_t)N * 16 + tb - 1) / tb, tb, 0, stream>>>(
            xl, xr, row_ptr, srcs, att + (size_t)L * DD, bias + (size_t)L * DD,
            out, Ahi, Alo, N, (L < 2) ? 1 : 0);
    }
}

// Round 4
// 557.276 us; speedup vs baseline: 2.0082x; 1.2123x over previous
//
#include <hip/hip_runtime.h>
#include <math.h>

#define DD 128
#define NEG 0.2f

typedef short short8 __attribute__((ext_vector_type(8)));
typedef float f32x4 __attribute__((ext_vector_type(4)));

__device__ __forceinline__ unsigned short f2bf(float f) {
    unsigned u = __float_as_uint(f);
    return (unsigned short)((u + 0x7fffu + ((u >> 16) & 1u)) >> 16);
}
__device__ __forceinline__ float bf2f(unsigned short h) {
    return __uint_as_float(((unsigned)h) << 16);
}

// exclusive scan in-place over sh[0..1024) (must be zero-padded), 256 threads.
__device__ void excl_scan_1024(int* sh, int* aux) {
    __syncthreads();
    int t = threadIdx.x;
    int base = t * 4;
    int a0 = sh[base], a1 = sh[base + 1], a2 = sh[base + 2], a3 = sh[base + 3];
    int s = a0 + a1 + a2 + a3;
    aux[t] = s;
    __syncthreads();
    for (int off = 1; off < 256; off <<= 1) {
        int v = (t >= off) ? aux[t - off] : 0;
        __syncthreads();
        aux[t] += v;
        __syncthreads();
    }
    int excl = aux[t] - s;
    sh[base] = excl;
    sh[base + 1] = excl + a0;
    sh[base + 2] = excl + a0 + a1;
    sh[base + 3] = excl + a0 + a1 + a2;
    __syncthreads();
}

// ---------------- CSR build: two-level partition ----------------
// Phase 1: coarse histogram of dst>>7 with LDS accumulation
__global__ __launch_bounds__(256) void k_histC(const int* __restrict__ dst,
                                               int* __restrict__ histC, int E, int CB) {
    __shared__ int h[1024];
    int t = threadIdx.x;
    for (int j = t; j < 1024; j += 256) h[j] = 0;
    __syncthreads();
    int stride = gridDim.x * 256;
    for (int i = blockIdx.x * 256 + t; i < E; i += stride)
        atomicAdd(&h[dst[i] >> 7], 1);
    __syncthreads();
    for (int j = t; j < CB; j += 256)
        if (h[j]) atomicAdd(&histC[j], h[j]);
}

// Phase 2: scan coarse histogram -> baseC[CB+1], cursorC[CB]
__global__ __launch_bounds__(256) void k_scanC2(const int* __restrict__ histC,
                                                int* __restrict__ baseC,
                                                int* __restrict__ cursorC, int CB) {
    __shared__ int sh[1024];
    __shared__ int aux[256];
    int t = threadIdx.x;
    for (int j = t; j < 1024; j += 256) sh[j] = (j < CB) ? histC[j] : 0;
    excl_scan_1024(sh, aux);
    for (int j = t; j <= CB; j += 256) {
        baseC[j] = sh[j];            // sh[CB] == E (pad zeros)
        if (j < CB) cursorC[j] = sh[j];
    }
}

// Phase 3: coarse partition. 8192 edges/block, LDS-staged, near-coalesced write.
#define CHUNK 8192
__global__ __launch_bounds__(256) void k_part3(const int* __restrict__ srcI,
                                               const int* __restrict__ dstI,
                                               int* __restrict__ cursorC,
                                               uint2* __restrict__ part,
                                               int E, int CB) {
    __shared__ int sh[1024];       // hist -> local start
    __shared__ int aux[256];
    __shared__ int resBase[1024];
    __shared__ int cur[1024];
    __shared__ uint2 stage[CHUNK];
    int t = threadIdx.x;
    int c0 = blockIdx.x * CHUNK;
    int cnt = E - c0; if (cnt > CHUNK) cnt = CHUNK;

    for (int j = t; j < 1024; j += 256) sh[j] = 0;
    __syncthreads();
    for (int i = t; i < cnt; i += 256)
        atomicAdd(&sh[dstI[c0 + i] >> 7], 1);
    __syncthreads();
    // reserve global ranges (pre-scan counts)
    for (int j = t; j < CB; j += 256) {
        int c = sh[j];
        resBase[j] = c ? atomicAdd(&cursorC[j], c) : 0;
    }
    excl_scan_1024(sh, aux);       // sh = chunk-local bucket starts
    for (int j = t; j < 1024; j += 256) cur[j] = sh[j];
    __syncthreads();
    // rank + stage
    for (int i = t; i < cnt; i += 256) {
        unsigned s = (unsigned)srcI[c0 + i];
        unsigned d = (unsigned)dstI[c0 + i];
        int b = (int)(d >> 7);
        int pos = atomicAdd(&cur[b], 1);
        stage[pos].x = s;
        stage[pos].y = d;
    }
    __syncthreads();
    // stream out: consecutive i -> mostly consecutive dest
    for (int i = t; i < cnt; i += 256) {
        uint2 v = stage[i];
        int b = (int)(v.y >> 7);
        part[resBase[b] + (i - sh[b])] = v;
    }
}

// Phase 4: fine counting-sort within each coarse bucket + row_ptr emission.
__global__ __launch_bounds__(256) void k_part4(const uint2* __restrict__ part,
                                               const int* __restrict__ baseC,
                                               int* __restrict__ srcs,
                                               int* __restrict__ row_ptr,
                                               int N) {
    __shared__ int hist[128];
    __shared__ int incl[128];
    __shared__ int cur[128];
    __shared__ unsigned srcS[8192];
    int b = blockIdx.x;
    int t = threadIdx.x;
    int base = baseC[b];
    int cnt = baseC[b + 1] - base;
    int node0 = b << 7;

    if (t < 128) hist[t] = 0;
    __syncthreads();
    for (int i = t; i < cnt; i += 256)
        atomicAdd(&hist[part[base + i].y & 127], 1);
    __syncthreads();
    if (t < 128) incl[t] = hist[t];
    __syncthreads();
    for (int off = 1; off < 128; off <<= 1) {
        int v = 0;
        if (t < 128 && t >= off) v = incl[t - off];
        __syncthreads();
        if (t < 128) incl[t] += v;
        __syncthreads();
    }
    if (t < 128) cur[t] = incl[t] - hist[t];
    __syncthreads();
    for (int i = t; i < cnt; i += 256) {
        uint2 e = part[base + i];
        int r = atomicAdd(&cur[e.y & 127], 1);
        if (r < 8192) srcS[r] = e.x;
    }
    __syncthreads();
    for (int i = t; i < cnt; i += 256)
        srcs[base + i] = (int)srcS[i];
    int nodes = N - node0; if (nodes > 128) nodes = 128;
    if (t < nodes) row_ptr[node0 + t + 1] = base + incl[t];
    if (b == 0 && t == 0) row_ptr[0] = 0;
}

// ---------------- split-float cast kernels ----------------
__global__ void k_castx(const float* __restrict__ x, unsigned short* __restrict__ hi,
                        unsigned short* __restrict__ lo, int n) {
    int i = (blockIdx.x * blockDim.x + threadIdx.x) * 4;
    if (i >= n) return;
    float4 v = *(const float4*)(x + i);
    unsigned short h[4], l[4];
    float f[4] = {v.x, v.y, v.z, v.w};
#pragma unroll
    for (int j = 0; j < 4; j++) {
        h[j] = f2bf(f[j]);
        l[j] = f2bf(f[j] - bf2f(h[j]));
    }
    *(uint2*)(hi + i) = *(uint2*)h;
    *(uint2*)(lo + i) = *(uint2*)l;
}

__global__ void k_castw(const float* __restrict__ Wl, const float* __restrict__ Wr,
                        unsigned short* __restrict__ Wth, unsigned short* __restrict__ Wtl) {
    int idx = blockIdx.x * blockDim.x + threadIdx.x;
    if (idx >= 3 * 256 * 128) return;
    int L = idx >> 15;
    int rem = idx & 32767;
    int nn = rem >> 7;
    int k = rem & 127;
    float v = (nn < 128) ? Wl[L * 16384 + k * 128 + nn]
                         : Wr[L * 16384 + k * 128 + (nn - 128)];
    unsigned short h = f2bf(v);
    Wth[idx] = h;
    Wtl[idx] = f2bf(v - bf2f(h));
}

// ---------------- MFMA GEMM: [xl|xr][M,128each] = A[M,128] @ W[128,256] ----------------
__global__ __launch_bounds__(256) void k_gemm(const unsigned short* __restrict__ Ahi,
                                              const unsigned short* __restrict__ Alo,
                                              const unsigned short* __restrict__ Wth,
                                              const unsigned short* __restrict__ Wtl,
                                              _Float16* __restrict__ xl, _Float16* __restrict__ xr,
                                              int M, int L) {
    __shared__ unsigned short sA[2][128][40];
    __shared__ unsigned short sB[2][128][40];
    int t = threadIdx.x;
    int lane = t & 63;
    int l15 = lane & 15;
    int quad = lane >> 4;
    int wave = t >> 6;
    int wm = wave & 1;
    int wn = wave >> 1;
    int r0 = blockIdx.x * 128;
    const unsigned short* WthL = Wth + ((size_t)L * 256 + blockIdx.y * 128) * 128;
    const unsigned short* WtlL = Wtl + ((size_t)L * 256 + blockIdx.y * 128) * 128;

    f32x4 acc[4][4] = {};

    for (int kc = 0; kc < 4; kc++) {
        int k0 = kc * 32;
        if (kc) __syncthreads();
#pragma unroll
        for (int i = 0; i < 2; i++) {
            int s = t + i * 256;
            int row = s >> 2;
            int kq = (s & 3) * 8;
            int gr = r0 + row; gr = gr < M ? gr : M - 1;
            uint2 va0 = *(const uint2*)(Ahi + (size_t)gr * DD + k0 + kq);
            uint2 va1 = *(const uint2*)(Ahi + (size_t)gr * DD + k0 + kq + 4);
            *(uint2*)&sA[0][row][kq] = va0;
            *(uint2*)&sA[0][row][kq + 4] = va1;
            uint2 vb0 = *(const uint2*)(Alo + (size_t)gr * DD + k0 + kq);
            uint2 vb1 = *(const uint2*)(Alo + (size_t)gr * DD + k0 + kq + 4);
            *(uint2*)&sA[1][row][kq] = vb0;
            *(uint2*)&sA[1][row][kq + 4] = vb1;
            uint2 wa0 = *(const uint2*)(WthL + (size_t)row * DD + k0 + kq);
            uint2 wa1 = *(const uint2*)(WthL + (size_t)row * DD + k0 + kq + 4);
            *(uint2*)&sB[0][row][kq] = wa0;
            *(uint2*)&sB[0][row][kq + 4] = wa1;
            uint2 wb0 = *(const uint2*)(WtlL + (size_t)row * DD + k0 + kq);
            uint2 wb1 = *(const uint2*)(WtlL + (size_t)row * DD + k0 + kq + 4);
            *(uint2*)&sB[1][row][kq] = wb0;
            *(uint2*)&sB[1][row][kq + 4] = wb1;
        }
        __syncthreads();

        union F8 { short8 v; uint2 u[2]; };
        F8 ah[4], al[4], bh[4], bl[4];
#pragma unroll
        for (int mt = 0; mt < 4; mt++) {
            const unsigned short* p = &sA[0][wm * 64 + mt * 16 + l15][quad * 8];
            ah[mt].u[0] = *(const uint2*)p; ah[mt].u[1] = *(const uint2*)(p + 4);
            const unsigned short* q = &sA[1][wm * 64 + mt * 16 + l15][quad * 8];
            al[mt].u[0] = *(const uint2*)q; al[mt].u[1] = *(const uint2*)(q + 4);
        }
#pragma unroll
        for (int nt = 0; nt < 4; nt++) {
            const unsigned short* p = &sB[0][wn * 64 + nt * 16 + l15][quad * 8];
            bh[nt].u[0] = *(const uint2*)p; bh[nt].u[1] = *(const uint2*)(p + 4);
            const unsigned short* q = &sB[1][wn * 64 + nt * 16 + l15][quad * 8];
            bl[nt].u[0] = *(const uint2*)q; bl[nt].u[1] = *(const uint2*)(q + 4);
        }
#pragma unroll
        for (int mt = 0; mt < 4; mt++)
#pragma unroll
            for (int nt = 0; nt < 4; nt++) {
                acc[mt][nt] = __builtin_amdgcn_mfma_f32_16x16x32_bf16(ah[mt].v, bh[nt].v, acc[mt][nt], 0, 0, 0);
                acc[mt][nt] = __builtin_amdgcn_mfma_f32_16x16x32_bf16(al[mt].v, bh[nt].v, acc[mt][nt], 0, 0, 0);
                acc[mt][nt] = __builtin_amdgcn_mfma_f32_16x16x32_bf16(ah[mt].v, bl[nt].v, acc[mt][nt], 0, 0, 0);
            }
    }

    _Float16* C = blockIdx.y ? xr : xl;
#pragma unroll
    for (int mt = 0; mt < 4; mt++)
#pragma unroll
        for (int r = 0; r < 4; r++) {
            int row = r0 + wm * 64 + mt * 16 + quad * 4 + r;
            if (row < M) {
#pragma unroll
                for (int nt = 0; nt < 4; nt++)
                    C[(size_t)row * DD + wn * 64 + nt * 16 + l15] = (_Float16)acc[mt][nt][r];
            }
        }
}

// ---------------- fused per-dst online-softmax attention + aggregate ----------------
__global__ __launch_bounds__(256) void k_attn(const _Float16* __restrict__ xl,
                                              const _Float16* __restrict__ xr,
                                              const int* __restrict__ row_ptr,
                                              const int* __restrict__ srcs,
                                              const float* __restrict__ att,
                                              const float* __restrict__ bias,
                                              float* __restrict__ outF,
                                              unsigned short* __restrict__ outHi,
                                              unsigned short* __restrict__ outLo,
                                              int n, int mode) {
    int gtid = blockIdx.x * blockDim.x + threadIdx.x;
    int d = gtid >> 4;
    if (d >= n) return;
    int l = threadIdx.x & 15;

    union H8 { uint4 q; _Float16 h[8]; };

    float atv[8], xrv[8];
    {
        float4 a0 = *(const float4*)(att + l * 8);
        float4 a1 = *(const float4*)(att + l * 8 + 4);
        atv[0] = a0.x; atv[1] = a0.y; atv[2] = a0.z; atv[3] = a0.w;
        atv[4] = a1.x; atv[5] = a1.y; atv[6] = a1.z; atv[7] = a1.w;
        H8 hr; hr.q = *(const uint4*)(xr + (size_t)d * DD + l * 8);
#pragma unroll
        for (int j = 0; j < 8; j++) xrv[j] = (float)hr.h[j];
    }

    int beg = row_ptr[d], end = row_ptr[d + 1];
    float m = -INFINITY, lse = 0.f;
    float av[8] = {0.f, 0.f, 0.f, 0.f, 0.f, 0.f, 0.f, 0.f};

    for (int i = beg; i < end; i++) {
        int s = srcs[i];
        H8 hx; hx.q = *(const uint4*)(xl + (size_t)s * DD + l * 8);
        float xv[8];
#pragma unroll
        for (int j = 0; j < 8; j++) xv[j] = (float)hx.h[j];
        float p = 0.f;
#pragma unroll
        for (int j = 0; j < 8; j++) {
            float z = xv[j] + xrv[j];
            z = z > 0.f ? z : NEG * z;
            p = fmaf(atv[j], z, p);
        }
        p += __shfl_xor(p, 1, 64);
        p += __shfl_xor(p, 2, 64);
        p += __shfl_xor(p, 4, 64);
        p += __shfl_xor(p, 8, 64);
        float nm = fmaxf(m, p);
        float sc = __expf(m - nm);
        float w  = __expf(p - nm);
#pragma unroll
        for (int j = 0; j < 8; j++) av[j] = av[j] * sc + xv[j] * w;
        lse = lse * sc + w;
        m = nm;
    }
    float inv = (end > beg) ? 1.0f / lse : 0.f;
    float o[8];
    {
        float4 b0 = *(const float4*)(bias + l * 8);
        float4 b1 = *(const float4*)(bias + l * 8 + 4);
        float bv[8] = {b0.x, b0.y, b0.z, b0.w, b1.x, b1.y, b1.z, b1.w};
#pragma unroll
        for (int j = 0; j < 8; j++) o[j] = av[j] * inv + bv[j];
    }
    if (mode) {
        union U8 { unsigned short s[8]; uint4 q; };
        U8 hh, ll;
#pragma unroll
        for (int j = 0; j < 8; j++) {
            float v = fmaxf(o[j], 0.f);
            hh.s[j] = f2bf(v);
            ll.s[j] = f2bf(v - bf2f(hh.s[j]));
        }
        *(uint4*)(outHi + (size_t)d * DD + l * 8) = hh.q;
        *(uint4*)(outLo + (size_t)d * DD + l * 8) = ll.q;
    } else {
        float4 o0 = {o[0], o[1], o[2], o[3]};
        float4 o1 = {o[4], o[5], o[6], o[7]};
        float* op = outF + (size_t)d * DD + l * 8;
        *(float4*)op = o0;
        *(float4*)(op + 4) = o1;
    }
}

// ---------------- launch ----------------
extern "C" void kernel_launch(void* const* d_in, const int* in_sizes, int n_in,
                              void* d_out, int out_size, void* d_ws, size_t ws_size,
                              hipStream_t stream) {
    const float* x    = (const float*)d_in[0];
    const float* Wl   = (const float*)d_in[1];
    const float* Wr   = (const float*)d_in[2];
    const float* att  = (const float*)d_in[3];
    const float* bias = (const float*)d_in[4];
    const int*   ei   = (const int*)d_in[5];

    int N = in_sizes[0] / DD;
    int E = in_sizes[5] / 2;
    const int* srcI = ei;
    const int* dstI = ei + E;
    float* out = (float*)d_out;
    int CB = (N + 127) >> 7;

    char* ws = (char*)d_ws;
    size_t off = 0;
    auto alloc = [&](size_t bytes) -> void* {
        void* p = ws + off;
        off += (bytes + 255) & ~(size_t)255;
        return p;
    };
    _Float16*       xl   = (_Float16*)alloc((size_t)N * DD * 2);
    _Float16*       xr   = (_Float16*)alloc((size_t)N * DD * 2);
    unsigned short* Ahi  = (unsigned short*)alloc((size_t)N * DD * 2);
    unsigned short* Alo  = (unsigned short*)alloc((size_t)N * DD * 2);
    unsigned short* Wth  = (unsigned short*)alloc((size_t)3 * 256 * 128 * 2);
    unsigned short* Wtl  = (unsigned short*)alloc((size_t)3 * 256 * 128 * 2);
    uint2* part    = (uint2*)alloc((size_t)E * 8);
    int*   srcs    = (int*)alloc((size_t)E * 4);
    int*   row_ptr = (int*)alloc((size_t)(N + 1) * 4);
    int*   histC   = (int*)alloc((size_t)(CB + 1) * 4);
    int*   baseC   = (int*)alloc((size_t)(CB + 1) * 4);
    int*   cursorC = (int*)alloc((size_t)(CB + 1) * 4);

    const int tb = 256;
    // CSR build (two-level partition)
    hipMemsetAsync(histC, 0, (size_t)CB * 4, stream);
    k_histC<<<256, 256, 0, stream>>>(dstI, histC, E, CB);
    k_scanC2<<<1, 256, 0, stream>>>(histC, baseC, cursorC, CB);
    k_part3<<<(E + CHUNK - 1) / CHUNK, 256, 0, stream>>>(srcI, dstI, cursorC, part, E, CB);
    k_part4<<<CB, 256, 0, stream>>>(part, baseC, srcs, row_ptr, N);

    // casts
    k_castw<<<(3 * 256 * 128 + tb - 1) / tb, tb, 0, stream>>>(Wl, Wr, Wth, Wtl);
    k_castx<<<((size_t)N * DD / 4 + tb - 1) / tb, tb, 0, stream>>>(x, Ahi, Alo, N * DD);

    int gX = (N + 127) / 128;
    for (int L = 0; L < 3; ++L) {
        k_gemm<<<dim3(gX, 2), 256, 0, stream>>>(Ahi, Alo, Wth, Wtl, xl, xr, N, L);
        k_attn<<<((size_t)N * 16 + tb - 1) / tb, tb, 0, stream>>>(
            xl, xr, row_ptr, srcs, att + (size_t)L * DD, bias + (size_t)L * DD,
            out, Ahi, Alo, N, (L < 2) ? 1 : 0);
    }
}

// Round 6
// 529.616 us; speedup vs baseline: 2.1131x; 1.0522x over previous
//
#include <hip/hip_runtime.h>
#include <math.h>

#define DD 128
#define NEG 0.2f

typedef short short8 __attribute__((ext_vector_type(8)));
typedef float f32x4 __attribute__((ext_vector_type(4)));
typedef float f32x2 __attribute__((ext_vector_type(2)));
typedef _Float16 h2v __attribute__((ext_vector_type(2)));

__device__ __forceinline__ unsigned short f2bf(float f) {
    unsigned u = __float_as_uint(f);
    return (unsigned short)((u + 0x7fffu + ((u >> 16) & 1u)) >> 16);
}
__device__ __forceinline__ float bf2f(unsigned short h) {
    return __uint_as_float(((unsigned)h) << 16);
}

// exclusive scan in-place over sh[0..1024) (must be zero-padded), 256 threads.
__device__ void excl_scan_1024(int* sh, int* aux) {
    __syncthreads();
    int t = threadIdx.x;
    int base = t * 4;
    int a0 = sh[base], a1 = sh[base + 1], a2 = sh[base + 2], a3 = sh[base + 3];
    int s = a0 + a1 + a2 + a3;
    aux[t] = s;
    __syncthreads();
    for (int off = 1; off < 256; off <<= 1) {
        int v = (t >= off) ? aux[t - off] : 0;
        __syncthreads();
        aux[t] += v;
        __syncthreads();
    }
    int excl = aux[t] - s;
    sh[base] = excl;
    sh[base + 1] = excl + a0;
    sh[base + 2] = excl + a0 + a1;
    sh[base + 3] = excl + a0 + a1 + a2;
    __syncthreads();
}

// ---------------- CSR build: two-level partition ----------------
__global__ __launch_bounds__(256) void k_histC(const int* __restrict__ dst,
                                               int* __restrict__ histC, int E, int CB) {
    __shared__ int h[1024];
    int t = threadIdx.x;
    for (int j = t; j < 1024; j += 256) h[j] = 0;
    __syncthreads();
    int stride = gridDim.x * 256;
    for (int i = blockIdx.x * 256 + t; i < E; i += stride)
        atomicAdd(&h[dst[i] >> 7], 1);
    __syncthreads();
    for (int j = t; j < CB; j += 256)
        if (h[j]) atomicAdd(&histC[j], h[j]);
}

__global__ __launch_bounds__(256) void k_scanC2(const int* __restrict__ histC,
                                                int* __restrict__ baseC,
                                                int* __restrict__ cursorC, int CB) {
    __shared__ int sh[1024];
    __shared__ int aux[256];
    int t = threadIdx.x;
    for (int j = t; j < 1024; j += 256) sh[j] = (j < CB) ? histC[j] : 0;
    excl_scan_1024(sh, aux);
    for (int j = t; j <= CB; j += 256) {
        baseC[j] = sh[j];
        if (j < CB) cursorC[j] = sh[j];
    }
}

#define CHUNK 8192
__global__ __launch_bounds__(256) void k_part3(const int* __restrict__ srcI,
                                               const int* __restrict__ dstI,
                                               int* __restrict__ cursorC,
                                               uint2* __restrict__ part,
                                               int E, int CB) {
    __shared__ int sh[1024];
    __shared__ int aux[256];
    __shared__ int resBase[1024];
    __shared__ int cur[1024];
    __shared__ uint2 stage[CHUNK];
    int t = threadIdx.x;
    int c0 = blockIdx.x * CHUNK;
    int cnt = E - c0; if (cnt > CHUNK) cnt = CHUNK;

    for (int j = t; j < 1024; j += 256) sh[j] = 0;
    __syncthreads();
    for (int i = t; i < cnt; i += 256)
        atomicAdd(&sh[dstI[c0 + i] >> 7], 1);
    __syncthreads();
    for (int j = t; j < CB; j += 256) {
        int c = sh[j];
        resBase[j] = c ? atomicAdd(&cursorC[j], c) : 0;
    }
    excl_scan_1024(sh, aux);
    for (int j = t; j < 1024; j += 256) cur[j] = sh[j];
    __syncthreads();
    for (int i = t; i < cnt; i += 256) {
        unsigned s = (unsigned)srcI[c0 + i];
        unsigned d = (unsigned)dstI[c0 + i];
        int b = (int)(d >> 7);
        int pos = atomicAdd(&cur[b], 1);
        stage[pos].x = s;
        stage[pos].y = d;
    }
    __syncthreads();
    for (int i = t; i < cnt; i += 256) {
        uint2 v = stage[i];
        int b = (int)(v.y >> 7);
        part[resBase[b] + (i - sh[b])] = v;
    }
}

__global__ __launch_bounds__(256) void k_part4(const uint2* __restrict__ part,
                                               const int* __restrict__ baseC,
                                               int* __restrict__ srcs,
                                               int* __restrict__ row_ptr,
                                               int N) {
    __shared__ int hist[128];
    __shared__ int incl[128];
    __shared__ int cur[128];
    __shared__ unsigned srcS[8192];
    int b = blockIdx.x;
    int t = threadIdx.x;
    int base = baseC[b];
    int cnt = baseC[b + 1] - base;
    int node0 = b << 7;

    if (t < 128) hist[t] = 0;
    __syncthreads();
    for (int i = t; i < cnt; i += 256)
        atomicAdd(&hist[part[base + i].y & 127], 1);
    __syncthreads();
    if (t < 128) incl[t] = hist[t];
    __syncthreads();
    for (int off = 1; off < 128; off <<= 1) {
        int v = 0;
        if (t < 128 && t >= off) v = incl[t - off];
        __syncthreads();
        if (t < 128) incl[t] += v;
        __syncthreads();
    }
    if (t < 128) cur[t] = incl[t] - hist[t];
    __syncthreads();
    for (int i = t; i < cnt; i += 256) {
        uint2 e = part[base + i];
        int r = atomicAdd(&cur[e.y & 127], 1);
        if (r < 8192) srcS[r] = e.x;
    }
    __syncthreads();
    for (int i = t; i < cnt; i += 256)
        srcs[base + i] = (int)srcS[i];
    int nodes = N - node0; if (nodes > 128) nodes = 128;
    if (t < nodes) row_ptr[node0 + t + 1] = base + incl[t];
    if (b == 0 && t == 0) row_ptr[0] = 0;
}

// ---------------- split-float cast kernels ----------------
__global__ void k_castx(const float* __restrict__ x, unsigned short* __restrict__ hi,
                        unsigned short* __restrict__ lo, int n) {
    int i = (blockIdx.x * blockDim.x + threadIdx.x) * 4;
    if (i >= n) return;
    float4 v = *(const float4*)(x + i);
    unsigned short h[4], l[4];
    float f[4] = {v.x, v.y, v.z, v.w};
#pragma unroll
    for (int j = 0; j < 4; j++) {
        h[j] = f2bf(f[j]);
        l[j] = f2bf(f[j] - bf2f(h[j]));
    }
    *(uint2*)(hi + i) = *(uint2*)h;
    *(uint2*)(lo + i) = *(uint2*)l;
}

__global__ void k_castw(const float* __restrict__ Wl, const float* __restrict__ Wr,
                        unsigned short* __restrict__ Wth, unsigned short* __restrict__ Wtl) {
    int idx = blockIdx.x * blockDim.x + threadIdx.x;
    if (idx >= 3 * 256 * 128) return;
    int L = idx >> 15;
    int rem = idx & 32767;
    int nn = rem >> 7;
    int k = rem & 127;
    float v = (nn < 128) ? Wl[L * 16384 + k * 128 + nn]
                         : Wr[L * 16384 + k * 128 + (nn - 128)];
    unsigned short h = f2bf(v);
    Wth[idx] = h;
    Wtl[idx] = f2bf(v - bf2f(h));
}

// ---------------- MFMA GEMM: [xl|xr][M,128each] = A[M,128] @ W[128,256] ----------------
__global__ __launch_bounds__(256) void k_gemm(const unsigned short* __restrict__ Ahi,
                                              const unsigned short* __restrict__ Alo,
                                              const unsigned short* __restrict__ Wth,
                                              const unsigned short* __restrict__ Wtl,
                                              _Float16* __restrict__ xl, _Float16* __restrict__ xr,
                                              int M, int L) {
    __shared__ unsigned short sA[2][128][40];
    __shared__ unsigned short sB[2][128][40];
    int t = threadIdx.x;
    int lane = t & 63;
    int l15 = lane & 15;
    int quad = lane >> 4;
    int wave = t >> 6;
    int wm = wave & 1;
    int wn = wave >> 1;
    int r0 = blockIdx.x * 128;
    const unsigned short* WthL = Wth + ((size_t)L * 256 + blockIdx.y * 128) * 128;
    const unsigned short* WtlL = Wtl + ((size_t)L * 256 + blockIdx.y * 128) * 128;

    f32x4 acc[4][4] = {};

    for (int kc = 0; kc < 4; kc++) {
        int k0 = kc * 32;
        if (kc) __syncthreads();
#pragma unroll
        for (int i = 0; i < 2; i++) {
            int s = t + i * 256;
            int row = s >> 2;
            int kq = (s & 3) * 8;
            int gr = r0 + row; gr = gr < M ? gr : M - 1;
            uint2 va0 = *(const uint2*)(Ahi + (size_t)gr * DD + k0 + kq);
            uint2 va1 = *(const uint2*)(Ahi + (size_t)gr * DD + k0 + kq + 4);
            *(uint2*)&sA[0][row][kq] = va0;
            *(uint2*)&sA[0][row][kq + 4] = va1;
            uint2 vb0 = *(const uint2*)(Alo + (size_t)gr * DD + k0 + kq);
            uint2 vb1 = *(const uint2*)(Alo + (size_t)gr * DD + k0 + kq + 4);
            *(uint2*)&sA[1][row][kq] = vb0;
            *(uint2*)&sA[1][row][kq + 4] = vb1;
            uint2 wa0 = *(const uint2*)(WthL + (size_t)row * DD + k0 + kq);
            uint2 wa1 = *(const uint2*)(WthL + (size_t)row * DD + k0 + kq + 4);
            *(uint2*)&sB[0][row][kq] = wa0;
            *(uint2*)&sB[0][row][kq + 4] = wa1;
            uint2 wb0 = *(const uint2*)(WtlL + (size_t)row * DD + k0 + kq);
            uint2 wb1 = *(const uint2*)(WtlL + (size_t)row * DD + k0 + kq + 4);
            *(uint2*)&sB[1][row][kq] = wb0;
            *(uint2*)&sB[1][row][kq + 4] = wb1;
        }
        __syncthreads();

        union F8 { short8 v; uint2 u[2]; };
        F8 ah[4], al[4], bh[4], bl[4];
#pragma unroll
        for (int mt = 0; mt < 4; mt++) {
            const unsigned short* p = &sA[0][wm * 64 + mt * 16 + l15][quad * 8];
            ah[mt].u[0] = *(const uint2*)p; ah[mt].u[1] = *(const uint2*)(p + 4);
            const unsigned short* q = &sA[1][wm * 64 + mt * 16 + l15][quad * 8];
            al[mt].u[0] = *(const uint2*)q; al[mt].u[1] = *(const uint2*)(q + 4);
        }
#pragma unroll
        for (int nt = 0; nt < 4; nt++) {
            const unsigned short* p = &sB[0][wn * 64 + nt * 16 + l15][quad * 8];
            bh[nt].u[0] = *(const uint2*)p; bh[nt].u[1] = *(const uint2*)(p + 4);
            const unsigned short* q = &sB[1][wn * 64 + nt * 16 + l15][quad * 8];
            bl[nt].u[0] = *(const uint2*)q; bl[nt].u[1] = *(const uint2*)(q + 4);
        }
#pragma unroll
        for (int mt = 0; mt < 4; mt++)
#pragma unroll
            for (int nt = 0; nt < 4; nt++) {
                acc[mt][nt] = __builtin_amdgcn_mfma_f32_16x16x32_bf16(ah[mt].v, bh[nt].v, acc[mt][nt], 0, 0, 0);
                acc[mt][nt] = __builtin_amdgcn_mfma_f32_16x16x32_bf16(al[mt].v, bh[nt].v, acc[mt][nt], 0, 0, 0);
                acc[mt][nt] = __builtin_amdgcn_mfma_f32_16x16x32_bf16(ah[mt].v, bl[nt].v, acc[mt][nt], 0, 0, 0);
            }
    }

    _Float16* C = blockIdx.y ? xr : xl;
#pragma unroll
    for (int mt = 0; mt < 4; mt++)
#pragma unroll
        for (int r = 0; r < 4; r++) {
            int row = r0 + wm * 64 + mt * 16 + quad * 4 + r;
            if (row < M) {
#pragma unroll
                for (int nt = 0; nt < 4; nt++)
                    C[(size_t)row * DD + wn * 64 + nt * 16 + l15] = (_Float16)acc[mt][nt][r];
            }
        }
}

// ---------------- fused per-dst attention + aggregate (no-max softmax) ----------------
// 16 lanes per dst, 8 elems/lane. Packed fp16 score (pk_add/pk_max/dot2), direct exp
// (scores bounded ~|p|<10 by construction; clamp +-60 as insurance), packed f32 accum.
__global__ __launch_bounds__(256) void k_attn(const _Float16* __restrict__ xl,
                                              const _Float16* __restrict__ xr,
                                              const int* __restrict__ row_ptr,
                                              const int* __restrict__ srcs,
                                              const float* __restrict__ att,
                                              const float* __restrict__ bias,
                                              float* __restrict__ outF,
                                              unsigned short* __restrict__ outHi,
                                              unsigned short* __restrict__ outLo,
                                              int n, int mode) {
    int gtid = blockIdx.x * blockDim.x + threadIdx.x;
    int d = gtid >> 4;
    if (d >= n) return;
    int l = threadIdx.x & 15;

    union Q { uint4 q; h2v h[4]; };

    h2v at[4], xrh[4];
    {
        float4 a0 = *(const float4*)(att + l * 8);
        float4 a1 = *(const float4*)(att + l * 8 + 4);
        at[0] = h2v{(_Float16)a0.x, (_Float16)a0.y};
        at[1] = h2v{(_Float16)a0.z, (_Float16)a0.w};
        at[2] = h2v{(_Float16)a1.x, (_Float16)a1.y};
        at[3] = h2v{(_Float16)a1.z, (_Float16)a1.w};
        Q hr; hr.q = *(const uint4*)(xr + (size_t)d * DD + l * 8);
#pragma unroll
        for (int j = 0; j < 4; j++) xrh[j] = hr.h[j];
    }
    const _Float16 cneg = (_Float16)NEG;

    int beg = row_ptr[d], end = row_ptr[d + 1];
    float lse = 0.f;
    f32x2 av[4] = {};

    for (int i = beg; i < end; i++) {
        int s = srcs[i];
        Q hx; hx.q = *(const uint4*)(xl + (size_t)s * DD + l * 8);
        float p = 0.f;
#pragma unroll
        for (int j = 0; j < 4; j++) {
            h2v z = hx.h[j] + xrh[j];
            h2v zl = __builtin_elementwise_max(z, z * cneg);  // leaky: max(z, 0.2z)
            p = __builtin_amdgcn_fdot2(zl, at[j], p, false);
        }
        p += __shfl_xor(p, 1, 64);
        p += __shfl_xor(p, 2, 64);
        p += __shfl_xor(p, 4, 64);
        p += __shfl_xor(p, 8, 64);
        p = fminf(fmaxf(p, -60.f), 60.f);
        float w = __expf(p);
        lse += w;
#pragma unroll
        for (int j = 0; j < 4; j++) {
            f32x2 xv = {(float)hx.h[j][0], (float)hx.h[j][1]};
            av[j] += xv * w;
        }
    }
    float inv = (end > beg) ? 1.0f / lse : 0.f;
    float o[8];
    {
        float4 b0 = *(const float4*)(bias + l * 8);
        float4 b1 = *(const float4*)(bias + l * 8 + 4);
        float bv[8] = {b0.x, b0.y, b0.z, b0.w, b1.x, b1.y, b1.z, b1.w};
#pragma unroll
        for (int j = 0; j < 4; j++) {
            o[2 * j]     = av[j][0] * inv + bv[2 * j];
            o[2 * j + 1] = av[j][1] * inv + bv[2 * j + 1];
        }
    }
    if (mode) {
        union U8 { unsigned short s[8]; uint4 q; };
        U8 hh, ll;
#pragma unroll
        for (int j = 0; j < 8; j++) {
            float v = fmaxf(o[j], 0.f);
            hh.s[j] = f2bf(v);
            ll.s[j] = f2bf(v - bf2f(hh.s[j]));
        }
        *(uint4*)(outHi + (size_t)d * DD + l * 8) = hh.q;
        *(uint4*)(outLo + (size_t)d * DD + l * 8) = ll.q;
    } else {
        float4 o0 = {o[0], o[1], o[2], o[3]};
        float4 o1 = {o[4], o[5], o[6], o[7]};
        float* op = outF + (size_t)d * DD + l * 8;
        *(float4*)op = o0;
        *(float4*)(op + 4) = o1;
    }
}

// ---------------- launch ----------------
extern "C" void kernel_launch(void* const* d_in, const int* in_sizes, int n_in,
                              void* d_out, int out_size, void* d_ws, size_t ws_size,
                              hipStream_t stream) {
    const float* x    = (const float*)d_in[0];
    const float* Wl   = (const float*)d_in[1];
    const float* Wr   = (const float*)d_in[2];
    const float* att  = (const float*)d_in[3];
    const float* bias = (const float*)d_in[4];
    const int*   ei   = (const int*)d_in[5];

    int N = in_sizes[0] / DD;
    int E = in_sizes[5] / 2;
    const int* srcI = ei;
    const int* dstI = ei + E;
    float* out = (float*)d_out;
    int CB = (N + 127) >> 7;

    char* ws = (char*)d_ws;
    size_t off = 0;
    auto alloc = [&](size_t bytes) -> void* {
        void* p = ws + off;
        off += (bytes + 255) & ~(size_t)255;
        return p;
    };
    _Float16*       xl   = (_Float16*)alloc((size_t)N * DD * 2);
    _Float16*       xr   = (_Float16*)alloc((size_t)N * DD * 2);
    unsigned short* Ahi  = (unsigned short*)alloc((size_t)N * DD * 2);
    unsigned short* Alo  = (unsigned short*)alloc((size_t)N * DD * 2);
    unsigned short* Wth  = (unsigned short*)alloc((size_t)3 * 256 * 128 * 2);
    unsigned short* Wtl  = (unsigned short*)alloc((size_t)3 * 256 * 128 * 2);
    uint2* part    = (uint2*)alloc((size_t)E * 8);
    int*   srcs    = (int*)alloc((size_t)E * 4);
    int*   row_ptr = (int*)alloc((size_t)(N + 1) * 4);
    int*   histC   = (int*)alloc((size_t)(CB + 1) * 4);
    int*   baseC   = (int*)alloc((size_t)(CB + 1) * 4);
    int*   cursorC = (int*)alloc((size_t)(CB + 1) * 4);

    const int tb = 256;
    (void)hipMemsetAsync(histC, 0, (size_t)CB * 4, stream);
    k_histC<<<256, 256, 0, stream>>>(dstI, histC, E, CB);
    k_scanC2<<<1, 256, 0, stream>>>(histC, baseC, cursorC, CB);
    k_part3<<<(E + CHUNK - 1) / CHUNK, 256, 0, stream>>>(srcI, dstI, cursorC, part, E, CB);
    k_part4<<<CB, 256, 0, stream>>>(part, baseC, srcs, row_ptr, N);

    k_castw<<<(3 * 256 * 128 + tb - 1) / tb, tb, 0, stream>>>(Wl, Wr, Wth, Wtl);
    k_castx<<<((size_t)N * DD / 4 + tb - 1) / tb, tb, 0, stream>>>(x, Ahi, Alo, N * DD);

    int gX = (N + 127) / 128;
    for (int L = 0; L < 3; ++L) {
        k_gemm<<<dim3(gX, 2), 256, 0, stream>>>(Ahi, Alo, Wth, Wtl, xl, xr, N, L);
        k_attn<<<((size_t)N * 16 + tb - 1) / tb, tb, 0, stream>>>(
            xl, xr, row_ptr, srcs, att + (size_t)L * DD, bias + (size_t)L * DD,
            out, Ahi, Alo, N, (L < 2) ? 1 : 0);
    }
}